// Round 13
// baseline (189.483 us; speedup 1.0000x reference)
//
#include <hip/hip_runtime.h>
#include <stdint.h>

typedef __attribute__((ext_vector_type(4))) float f32x4;
typedef __attribute__((ext_vector_type(8))) __bf16 bf16x8;
typedef __attribute__((ext_vector_type(4))) unsigned int u32x4;
typedef unsigned short u16;

#define B_DIM 2
#define T_DIM 2048
#define C_DIM 2048
#define H_Q   16
#define H_KV  4
#define HD    128
#define NQKV  3072            // 2048 q | 512 k | 512 v
#define MTOK  4096            // B*T
#define RMS_EPS 1.1920928955078125e-07f
// 1/sqrt(128) * log2(e), folded into q's rms scale so S comes out in exp2 domain
#define Q_SCALE 0.12751749f

__device__ __forceinline__ u16 f2bf(float f) {
  union { float f; unsigned int u; } v; v.f = f;
  unsigned int r = v.u + 0x7FFFu + ((v.u >> 16) & 1u);   // RNE
  return (u16)(r >> 16);
}
__device__ __forceinline__ float bf2f(u16 h) {
  union { unsigned int u; float f; } v; v.u = ((unsigned int)h) << 16;
  return v.f;
}
__device__ __forceinline__ f32x4 mfma16(bf16x8 a, bf16x8 b, f32x4 c) {
  return __builtin_amdgcn_mfma_f32_16x16x32_bf16(a, b, c, 0, 0, 0);
}
// async global->LDS, 16B per lane; lds base must be wave-uniform (HW: base + lane*16)
__device__ __forceinline__ void gl_lds16(const void* g, void* l) {
  __builtin_amdgcn_global_load_lds(
      (const __attribute__((address_space(1))) unsigned int*)g,
      (__attribute__((address_space(3))) unsigned int*)l, 16, 0, 0);
}

// ---------------- prep: weight transposes (blocks 0..2559) + x cast (rest) ----------------
// Transpose is fully vectorized: float4 global loads, float4 LDS writes (row pad
// 68 words keeps 16B alignment; transposed reads land 2-way bank-aliased = free),
// packed uint2 (4x bf16) stores.
__global__ __launch_bounds__(256) void prep_kernel(const float* __restrict__ x,
                                                   const float* __restrict__ wq,
                                                   const float* __restrict__ wk,
                                                   const float* __restrict__ wv,
                                                   const float* __restrict__ wo,
                                                   u16* __restrict__ xb,
                                                   u16* __restrict__ wqkvb,
                                                   u16* __restrict__ wob) {
  __shared__ __align__(16) float tile[64][68];
  int bid = blockIdx.x, t = threadIdx.x;
  if (bid < 2560) {                       // transpose+cast fp32 [K][N] -> bf16 [N][2048]
    int nb = bid % 80, kb = bid / 80;
    const float* src; u16* dst; int srcN, nloc;
    if (nb < 32)      { src = wq; srcN = 2048; nloc = nb;      dst = wqkvb; }
    else if (nb < 40) { src = wk; srcN = 512;  nloc = nb - 32; dst = wqkvb + (size_t)2048 * 2048; }
    else if (nb < 48) { src = wv; srcN = 512;  nloc = nb - 40; dst = wqkvb + (size_t)2560 * 2048; }
    else              { src = wo; srcN = 2048; nloc = nb - 48; dst = wob; }
    int n0 = nloc * 64, k0 = kb * 64;
    #pragma unroll
    for (int idx = t; idx < 1024; idx += 256) {
      int r = idx >> 4, c4 = (idx & 15) * 4;      // r = k-local, c4 = n-local
      *(float4*)&tile[r][c4] = *(const float4*)&src[(size_t)(k0 + r) * srcN + n0 + c4];
    }
    __syncthreads();
    #pragma unroll
    for (int idx = t; idx < 1024; idx += 256) {
      int r = idx >> 4, c4 = (idx & 15) * 4;      // r = n-local, c4 = k-local
      unsigned int a0 = f2bf(tile[c4 + 0][r]), a1 = f2bf(tile[c4 + 1][r]);
      unsigned int a2 = f2bf(tile[c4 + 2][r]), a3 = f2bf(tile[c4 + 3][r]);
      uint2 w = make_uint2(a0 | (a1 << 16), a2 | (a3 << 16));
      *(uint2*)&dst[(size_t)(n0 + r) * 2048 + k0 + c4] = w;
    }
  } else {                                // cast x
    int i = ((bid - 2560) * 256 + t) * 4;
    if (i >= MTOK * C_DIM) return;
    float4 v = *(const float4*)(x + i);
    u16 o0 = f2bf(v.x), o1 = f2bf(v.y), o2 = f2bf(v.z), o3 = f2bf(v.w);
    unsigned int lo = (unsigned int)o0 | ((unsigned int)o1 << 16);
    unsigned int hi = (unsigned int)o2 | ((unsigned int)o3 << 16);
    *(uint2*)(xb + i) = make_uint2(lo, hi);
  }
}

// ---------------- rope+rms (in place on q,k) + V^T precompute, one dispatch ----------------
// q heads additionally scaled by Q_SCALE so attention scores land in exp2 domain.
__global__ __launch_bounds__(256) void ropevt_kernel(u16* __restrict__ qkv,
                                                     const float* __restrict__ cosb,
                                                     const float* __restrict__ sinb,
                                                     u16* __restrict__ vt) {
  __shared__ __align__(16) u16 tile[64][136];
  int bid = blockIdx.x, tid = threadIdx.x;
  if (bid < 256) {                        // vtrans: qkv v-section -> vt[b][kvh][d][T]
    int tt0 = (bid & 31) * 64;
    int kvh = (bid >> 5) & 3;
    int b   = bid >> 7;
    const u16* vp = qkv + ((size_t)b * T_DIM + tt0) * NQKV + C_DIM + H_KV * HD + kvh * HD;
    #pragma unroll
    for (int i = 0; i < 4; ++i) {
      int cid = tid + i * 256;
      int r = cid >> 4, c = cid & 15;
      u32x4 v = *(const u32x4*)(vp + (size_t)r * NQKV + c * 8);
      *(u32x4*)&tile[r][c * 8] = v;
    }
    __syncthreads();
    u16* op = vt + ((size_t)(b * H_KV + kvh) * HD) * T_DIM + tt0;
    #pragma unroll
    for (int i = 0; i < 4; ++i) {
      int cid = tid + i * 256;
      int d = cid >> 3, tc = cid & 7;
      u16 vals[8];
      #pragma unroll
      for (int j = 0; j < 8; ++j) vals[j] = tile[tc * 8 + j][d];
      u32x4 w;
      w.x = (unsigned int)vals[0] | ((unsigned int)vals[1] << 16);
      w.y = (unsigned int)vals[2] | ((unsigned int)vals[3] << 16);
      w.z = (unsigned int)vals[4] | ((unsigned int)vals[5] << 16);
      w.w = (unsigned int)vals[6] | ((unsigned int)vals[7] << 16);
      *(u32x4*)(op + (size_t)d * T_DIM + tc * 8) = w;
    }
  } else {                                // rope+rms: one wave per (token, head)
    int gw = ((bid - 256) * 256 + tid) >> 6;
    int lane = tid & 63;
    int hh = gw % (H_Q + H_KV);
    int tok = gw / (H_Q + H_KV);
    int t = tok & (T_DIM - 1);
    bool isq = (hh < H_Q);
    int base = isq ? hh * HD : (C_DIM + (hh - H_Q) * HD);
    u16* p = qkv + (size_t)tok * NQKV + base;
    float x1 = bf2f(p[lane]);
    float x2 = bf2f(p[lane + 64]);
    float c = cosb[t * 64 + lane];
    float s = sinb[t * 64 + lane];
    float o1 =  x1 * c + x2 * s;
    float o2 = -x1 * s + x2 * c;
    float ss = o1 * o1 + o2 * o2;
    #pragma unroll
    for (int off = 1; off < 64; off <<= 1) ss += __shfl_xor(ss, off);
    float r = rsqrtf(ss * (1.0f / 128.0f) + RMS_EPS);
    if (isq) r *= Q_SCALE;
    p[lane]      = f2bf(o1 * r);
    p[lane + 64] = f2bf(o2 * r);
  }
}

// ---------------- bf16 GEMM: C[M][N] = A[M][K] * Bt[N][K]^T ----------------
// 128x128 tile, BK=64, 4 waves, gl_lds staging (pre-swizzled source).
// Natural block order: consecutive blockIdx.x share the same A-panel in L2
// (XCD swizzle tried R11/R12: FETCH 72->86 MB, dur +1 -- reverted).
template<int BF16OUT>
__global__ __launch_bounds__(256) void gemm_bt_kernel(const u16* __restrict__ A,
                                                      const u16* __restrict__ Bt,
                                                      void* __restrict__ Cv,
                                                      int M, int N, int K) {
  __shared__ __align__(16) u16 Asm[128 * 64];
  __shared__ __align__(16) u16 Bsm[128 * 64];
  const int tid = threadIdx.x;
  const int lane = tid & 63;
  const int wid = tid >> 6;
  const int m0 = blockIdx.y * 128, n0 = blockIdx.x * 128;
  const int wm = (wid >> 1) * 64, wn = (wid & 1) * 64;
  const int l15 = lane & 15, l4 = lane >> 4;
  const int csrc = (lane & 7) ^ (lane >> 3);      // pre-swizzled source chunk
  f32x4 acc[4][4] = {};

  for (int k0 = 0; k0 < K; k0 += 64) {
    __syncthreads();
    #pragma unroll
    for (int i = 0; i < 4; ++i) {
      int g = wid * 4 + i;
      int row = g * 8 + (lane >> 3);
      gl_lds16(A  + (size_t)(m0 + row) * K + k0 + csrc * 8, (char*)Asm + g * 1024);
      gl_lds16(Bt + (size_t)(n0 + row) * K + k0 + csrc * 8, (char*)Bsm + g * 1024);
    }
    __syncthreads();
    #pragma unroll
    for (int ks = 0; ks < 2; ++ks) {
      bf16x8 af[4], bfr[4];
      #pragma unroll
      for (int mf = 0; mf < 4; ++mf) {
        int r = wm + mf * 16 + l15;
        int bo = r * 128 + (((ks * 4 + l4) ^ (r & 7)) * 16);
        af[mf] = __builtin_bit_cast(bf16x8, *(const u32x4*)((const char*)Asm + bo));
      }
      #pragma unroll
      for (int nf = 0; nf < 4; ++nf) {
        int r = wn + nf * 16 + l15;
        int bo = r * 128 + (((ks * 4 + l4) ^ (r & 7)) * 16);
        bfr[nf] = __builtin_bit_cast(bf16x8, *(const u32x4*)((const char*)Bsm + bo));
      }
      #pragma unroll
      for (int mf = 0; mf < 4; ++mf)
        #pragma unroll
        for (int nf = 0; nf < 4; ++nf)
          acc[mf][nf] = mfma16(af[mf], bfr[nf], acc[mf][nf]);
    }
  }
  #pragma unroll
  for (int mf = 0; mf < 4; ++mf)
    #pragma unroll
    for (int nf = 0; nf < 4; ++nf)
      #pragma unroll
      for (int reg = 0; reg < 4; ++reg) {
        int row = m0 + wm + mf * 16 + l4 * 4 + reg;
        int col = n0 + wn + nf * 16 + l15;
        float v = acc[mf][nf][reg];
        if (BF16OUT) ((u16*)Cv)[(size_t)row * N + col] = f2bf(v);
        else         ((float*)Cv)[(size_t)row * N + col] = v;
      }
}

// ---------------- sliding-window GQA flash attention, 2 heads per block ----------------
// Block = 64 q-rows x 2 q-heads of one (b,kvh); 8 waves (512 thr): wave w = head
// (w&1), rows (w>>1)*16. Each staged 32KB K/V tile feeds 2 heads. LDS 80KB ->
// 2 blocks/CU via __launch_bounds__(512, 2) (2nd arg = blocks/CU: R11's (512,4)
// forced VGPR 64 and spilled 330MB to scratch; (512,2) -> VGPR cap 128, fits).
__global__ __launch_bounds__(512, 2) void attn_kernel(const u16* __restrict__ qkv,
                                                      const u16* __restrict__ vt,
                                                      u16* __restrict__ yb,
                                                      const int* __restrict__ wsz_p) {
  __shared__ __align__(16) u16 Ksm[2][64 * 128];  // [key][d], 16-chunk swizzle ^(key&15)
  __shared__ __align__(16) u16 Vsm[2][128 * 64];  // [d][key], 8-chunk swizzle ^(d&7)
  __shared__ __align__(16) u16 Psm[8 * 16 * 64];  // per-wave P 16x64, swizzled

  const int W = wsz_p[0];
  const int tid = threadIdx.x, lane = tid & 63, wid = tid >> 6;
  const int l15 = lane & 15, l4 = lane >> 4;
  const int bid = blockIdx.x;
  const int sub = bid & 15;
  const int qt  = 31 - (bid >> 4);       // longest first (LPT)
  const int b    = sub >> 3;
  const int kvh  = (sub >> 1) & 3;
  const int pair = sub & 1;
  const int h    = kvh * 4 + pair * 2 + (wid & 1);   // this wave's q-head
  const size_t tokb = (size_t)b * T_DIM;
  const u16* vtb = vt + ((size_t)(b * H_KV + kvh) * HD) * T_DIM;
  const int rbase = qt * 64 + (wid >> 1) * 16;

  // staging: 32 issues over 8 waves (2 K + 2 V each), 1KB per issue
  auto stage = [&](int kt, int bufsel) {
    const u16* kp = qkv + (tokb + kt * 64) * NQKV + C_DIM + kvh * HD;
    #pragma unroll
    for (int i = 0; i < 2; ++i) {
      int g = wid * 2 + i;
      int row = g * 4 + (lane >> 4);
      int cs = (lane & 15) ^ (row & 15);
      gl_lds16(kp + (size_t)row * NQKV + cs * 8, (char*)Ksm[bufsel] + g * 1024);
    }
    const u16* vp = vtb + kt * 64;
    #pragma unroll
    for (int i = 0; i < 2; ++i) {
      int g = wid * 2 + i;
      int d = g * 8 + (lane >> 3);
      int cs = (lane & 7) ^ (d & 7);
      gl_lds16(vp + (size_t)d * T_DIM + cs * 8, (char*)Vsm[bufsel] + g * 1024);
    }
  };

  bf16x8 qf[4];
  {
    int r = rbase + l15;
    const u16* qp = qkv + (tokb + r) * NQKV + h * HD;
    #pragma unroll
    for (int ks = 0; ks < 4; ++ks)
      qf[ks] = __builtin_bit_cast(bf16x8, *(const u32x4*)(qp + ks * 32 + l4 * 8));
  }

  const u32x4 onesu = {0x3F803F80u, 0x3F803F80u, 0x3F803F80u, 0x3F803F80u};
  const bf16x8 onesf = __builtin_bit_cast(bf16x8, onesu);   // 8 x bf16(1.0)

  f32x4 yacc[8] = {};
  f32x4 ylsum = {0.f, 0.f, 0.f, 0.f};    // softmax denominator, via P @ ones
  float mrow[4];
  #pragma unroll
  for (int rg = 0; rg < 4; ++rg) mrow[rg] = -3.0e38f;

  int smin = qt * 64 - W; if (smin < 0) smin = 0;
  const int t0 = smin >> 6;
  char* pbase = (char*)Psm + wid * 2048;

  stage(t0, 0);
  __syncthreads();
  int cur = 0;

  for (int kt = t0; kt <= qt; ++kt) {
    if (kt < qt) stage(kt + 1, cur ^ 1);

    const int slo = kt * 64;
    bool active = (slo <= rbase + 15) && ((rbase - (slo + 63)) <= W);
    if (active) {
      // S = Q K^T (exp2 domain; Q pre-scaled)
      float Sc[4][4];
      #pragma unroll
      for (int nf = 0; nf < 4; ++nf) {
        f32x4 sa = {0.f, 0.f, 0.f, 0.f};
        int key = nf * 16 + l15;
        #pragma unroll
        for (int ks = 0; ks < 4; ++ks) {
          int bo = key * 256 + (((ks * 4 + l4) ^ (key & 15)) * 16);
          bf16x8 kf = __builtin_bit_cast(bf16x8, *(const u32x4*)((const char*)Ksm[cur] + bo));
          sa = mfma16(qf[ks], kf, sa);
        }
        #pragma unroll
        for (int rg = 0; rg < 4; ++rg) Sc[nf][rg] = sa[rg];
      }
      // mask only when tile not fully valid for this wave
      bool fullvalid = ((slo + 63) <= rbase) && ((rbase + 15 - slo) <= W);
      if (!fullvalid) {
        #pragma unroll
        for (int nf = 0; nf < 4; ++nf) {
          int s = slo + nf * 16 + l15;
          #pragma unroll
          for (int rg = 0; rg < 4; ++rg) {
            int r = rbase + l4 * 4 + rg;
            if (s > r || (r - s) > W) Sc[nf][rg] = -3.0e38f;
          }
        }
      }
      // tile max per row (wave-reduced over the 16 key-lanes)
      float tmax[4];
      #pragma unroll
      for (int rg = 0; rg < 4; ++rg) {
        float tm = fmaxf(fmaxf(Sc[0][rg], Sc[1][rg]), fmaxf(Sc[2][rg], Sc[3][rg]));
        #pragma unroll
        for (int off = 1; off < 16; off <<= 1) tm = fmaxf(tm, __shfl_xor(tm, off));
        tmax[rg] = tm;
      }
      // T13 defer-rescale: skip when no row's max grew by >8 (P bounded by 2^8)
      bool small = tmax[0] <= mrow[0] + 8.f && tmax[1] <= mrow[1] + 8.f &&
                   tmax[2] <= mrow[2] + 8.f && tmax[3] <= mrow[3] + 8.f;
      if (!__all(small)) {
        f32x4 fv;
        #pragma unroll
        for (int rg = 0; rg < 4; ++rg) {
          float mnew = fmaxf(mrow[rg], tmax[rg]);
          fv[rg] = exp2f(fmaxf(mrow[rg], -1.0e30f) - fmaxf(mnew, -1.0e30f));
          mrow[rg] = mnew;
        }
        #pragma unroll
        for (int nf2 = 0; nf2 < 8; ++nf2) yacc[nf2] *= fv;
        ylsum *= fv;
      }
      float mc[4];
      #pragma unroll
      for (int rg = 0; rg < 4; ++rg) mc[rg] = fmaxf(mrow[rg], -1.0e30f);
      // P = exp2(S - m), truncation-cast to bf16 -> wave-private LDS
      #pragma unroll
      for (int nf = 0; nf < 4; ++nf)
        #pragma unroll
        for (int rg = 0; rg < 4; ++rg) {
          float pv = exp2f(Sc[nf][rg] - mc[rg]);
          unsigned int pbits = __builtin_bit_cast(unsigned int, pv);
          int q   = l4 * 4 + rg;
          int key = nf * 16 + l15;
          int bo = q * 128 + (((key >> 3) ^ (q & 7)) * 16) + (key & 7) * 2;
          *(u16*)(pbase + bo) = (u16)(pbits >> 16);
        }

      // PV: y(16x128) += P(16x64) @ V(64x128);  denominator: ylsum += P @ 1
      #pragma unroll
      for (int ks2 = 0; ks2 < 2; ++ks2) {
        int boA = l15 * 128 + (((ks2 * 4 + l4) ^ (l15 & 7)) * 16);
        bf16x8 pa = __builtin_bit_cast(bf16x8, *(const u32x4*)(pbase + boA));
        ylsum = mfma16(pa, onesf, ylsum);
        #pragma unroll
        for (int nf2 = 0; nf2 < 8; ++nf2) {
          int d = nf2 * 16 + l15;
          int boB = d * 128 + (((ks2 * 4 + l4) ^ (d & 7)) * 16);
          bf16x8 vf = __builtin_bit_cast(bf16x8, *(const u32x4*)((const char*)Vsm[cur] + boB));
          yacc[nf2] = mfma16(pa, vf, yacc[nf2]);
        }
      }
    }
    __syncthreads();
    cur ^= 1;
  }

  // normalize + write y (bf16)
  #pragma unroll
  for (int nf2 = 0; nf2 < 8; ++nf2)
    #pragma unroll
    for (int rg = 0; rg < 4; ++rg) {
      int r = rbase + l4 * 4 + rg;
      float v = yacc[nf2][rg] / ylsum[rg];
      yb[(tokb + r) * (size_t)C_DIM + h * HD + nf2 * 16 + l15] = f2bf(v);
    }
}

// ---------------- launch ----------------
extern "C" void kernel_launch(void* const* d_in, const int* in_sizes, int n_in,
                              void* d_out, int out_size, void* d_ws, size_t ws_size,
                              hipStream_t stream) {
  const float* x    = (const float*)d_in[0];
  const float* cosb = (const float*)d_in[1];
  const float* sinb = (const float*)d_in[2];
  const float* wq   = (const float*)d_in[3];
  const float* wk   = (const float*)d_in[4];
  const float* wv   = (const float*)d_in[5];
  const float* wo   = (const float*)d_in[6];
  const int*   wsz  = (const int*)d_in[7];

  char* ws = (char*)d_ws;
  u16* xb    = (u16*)(ws);                       // 16 MB (dead after QKV GEMM)
  u16* qkvb  = (u16*)(ws + (size_t)16777216);    // 24 MB
  u16* wqkvb = (u16*)(ws + (size_t)41943040);    // 12 MB, [3072][2048]
  u16* wob   = (u16*)(ws + (size_t)54525952);    // 8 MB,  [2048][2048]
  u16* ybuf  = (u16*)(ws + (size_t)62914560);    // 16 MB
  u16* vtb   = (u16*)(ws);                       // 4 MB, reuses xb region

  prep_kernel<<<2560 + 8192, 256, 0, stream>>>(x, wq, wk, wv, wo, xb, wqkvb, wob);
  gemm_bt_kernel<1><<<dim3(NQKV / 128, MTOK / 128), 256, 0, stream>>>(xb, wqkvb, qkvb, MTOK, NQKV, C_DIM);
  ropevt_kernel<<<256 + (MTOK * (H_Q + H_KV)) / 4, 256, 0, stream>>>(qkvb, cosb, sinb, vtb);
  attn_kernel<<<B_DIM * H_KV * 2 * (T_DIM / 64), 512, 0, stream>>>(qkvb, vtb, ybuf, wsz);
  gemm_bt_kernel<0><<<dim3(C_DIM / 128, MTOK / 128), 256, 0, stream>>>(ybuf, wob, d_out, MTOK, C_DIM, C_DIM);
}

// Round 14
// 187.329 us; speedup vs baseline: 1.0115x; 1.0115x over previous
//
#include <hip/hip_runtime.h>
#include <stdint.h>

typedef __attribute__((ext_vector_type(4))) float f32x4;
typedef __attribute__((ext_vector_type(8))) __bf16 bf16x8;
typedef __attribute__((ext_vector_type(4))) unsigned int u32x4;
typedef unsigned short u16;

#define B_DIM 2
#define T_DIM 2048
#define C_DIM 2048
#define H_Q   16
#define H_KV  4
#define HD    128
#define NQKV  3072            // 2048 q | 512 k | 512 v
#define MTOK  4096            // B*T
#define RMS_EPS 1.1920928955078125e-07f
// 1/sqrt(128) * log2(e), folded into q's rms scale so S comes out in exp2 domain
#define Q_SCALE 0.12751749f

__device__ __forceinline__ u16 f2bf(float f) {
  union { float f; unsigned int u; } v; v.f = f;
  unsigned int r = v.u + 0x7FFFu + ((v.u >> 16) & 1u);   // RNE
  return (u16)(r >> 16);
}
__device__ __forceinline__ float bf2f(u16 h) {
  union { unsigned int u; float f; } v; v.u = ((unsigned int)h) << 16;
  return v.f;
}
__device__ __forceinline__ f32x4 mfma16(bf16x8 a, bf16x8 b, f32x4 c) {
  return __builtin_amdgcn_mfma_f32_16x16x32_bf16(a, b, c, 0, 0, 0);
}
// async global->LDS, 16B per lane; lds base must be wave-uniform (HW: base + lane*16)
__device__ __forceinline__ void gl_lds16(const void* g, void* l) {
  __builtin_amdgcn_global_load_lds(
      (const __attribute__((address_space(1))) unsigned int*)g,
      (__attribute__((address_space(3))) unsigned int*)l, 16, 0, 0);
}

// ---------------- prep: weight transposes (blocks 0..2559) + x cast (rest) ----------------
__global__ __launch_bounds__(256) void prep_kernel(const float* __restrict__ x,
                                                   const float* __restrict__ wq,
                                                   const float* __restrict__ wk,
                                                   const float* __restrict__ wv,
                                                   const float* __restrict__ wo,
                                                   u16* __restrict__ xb,
                                                   u16* __restrict__ wqkvb,
                                                   u16* __restrict__ wob) {
  __shared__ float tile[64][65];
  int bid = blockIdx.x, t = threadIdx.x;
  if (bid < 2560) {                       // transpose+cast fp32 [K][N] -> bf16 [N][2048]
    int nb = bid % 80, kb = bid / 80;
    const float* src; u16* dst; int srcN, nloc;
    if (nb < 32)      { src = wq; srcN = 2048; nloc = nb;      dst = wqkvb; }
    else if (nb < 40) { src = wk; srcN = 512;  nloc = nb - 32; dst = wqkvb + (size_t)2048 * 2048; }
    else if (nb < 48) { src = wv; srcN = 512;  nloc = nb - 40; dst = wqkvb + (size_t)2560 * 2048; }
    else              { src = wo; srcN = 2048; nloc = nb - 48; dst = wob; }
    int n0 = nloc * 64, k0 = kb * 64;
    #pragma unroll
    for (int idx = t; idx < 4096; idx += 256) {
      int r = idx >> 6, c = idx & 63;
      tile[r][c] = src[(size_t)(k0 + r) * srcN + n0 + c];
    }
    __syncthreads();
    #pragma unroll
    for (int idx = t; idx < 4096; idx += 256) {
      int r = idx >> 6, c = idx & 63;
      dst[(size_t)(n0 + r) * 2048 + k0 + c] = f2bf(tile[c][r]);
    }
  } else {                                // cast x
    int i = ((bid - 2560) * 256 + t) * 4;
    if (i >= MTOK * C_DIM) return;
    float4 v = *(const float4*)(x + i);
    u16 o0 = f2bf(v.x), o1 = f2bf(v.y), o2 = f2bf(v.z), o3 = f2bf(v.w);
    unsigned int lo = (unsigned int)o0 | ((unsigned int)o1 << 16);
    unsigned int hi = (unsigned int)o2 | ((unsigned int)o3 << 16);
    *(uint2*)(xb + i) = make_uint2(lo, hi);
  }
}

// ---------------- rope+rms (in place on q,k) + V^T precompute, one dispatch ----------------
// q heads additionally scaled by Q_SCALE so attention scores land in exp2 domain.
__global__ __launch_bounds__(256) void ropevt_kernel(u16* __restrict__ qkv,
                                                     const float* __restrict__ cosb,
                                                     const float* __restrict__ sinb,
                                                     u16* __restrict__ vt) {
  __shared__ __align__(16) u16 tile[64][136];
  int bid = blockIdx.x, tid = threadIdx.x;
  if (bid < 256) {                        // vtrans: qkv v-section -> vt[b][kvh][d][T]
    int tt0 = (bid & 31) * 64;
    int kvh = (bid >> 5) & 3;
    int b   = bid >> 7;
    const u16* vp = qkv + ((size_t)b * T_DIM + tt0) * NQKV + C_DIM + H_KV * HD + kvh * HD;
    #pragma unroll
    for (int i = 0; i < 4; ++i) {
      int cid = tid + i * 256;
      int r = cid >> 4, c = cid & 15;
      u32x4 v = *(const u32x4*)(vp + (size_t)r * NQKV + c * 8);
      *(u32x4*)&tile[r][c * 8] = v;
    }
    __syncthreads();
    u16* op = vt + ((size_t)(b * H_KV + kvh) * HD) * T_DIM + tt0;
    #pragma unroll
    for (int i = 0; i < 4; ++i) {
      int cid = tid + i * 256;
      int d = cid >> 3, tc = cid & 7;
      u16 vals[8];
      #pragma unroll
      for (int j = 0; j < 8; ++j) vals[j] = tile[tc * 8 + j][d];
      u32x4 w;
      w.x = (unsigned int)vals[0] | ((unsigned int)vals[1] << 16);
      w.y = (unsigned int)vals[2] | ((unsigned int)vals[3] << 16);
      w.z = (unsigned int)vals[4] | ((unsigned int)vals[5] << 16);
      w.w = (unsigned int)vals[6] | ((unsigned int)vals[7] << 16);
      *(u32x4*)(op + (size_t)d * T_DIM + tc * 8) = w;
    }
  } else {                                // rope+rms: one wave per (token, head)
    int gw = ((bid - 256) * 256 + tid) >> 6;
    int lane = tid & 63;
    int hh = gw % (H_Q + H_KV);
    int tok = gw / (H_Q + H_KV);
    int t = tok & (T_DIM - 1);
    bool isq = (hh < H_Q);
    int base = isq ? hh * HD : (C_DIM + (hh - H_Q) * HD);
    u16* p = qkv + (size_t)tok * NQKV + base;
    float x1 = bf2f(p[lane]);
    float x2 = bf2f(p[lane + 64]);
    float c = cosb[t * 64 + lane];
    float s = sinb[t * 64 + lane];
    float o1 =  x1 * c + x2 * s;
    float o2 = -x1 * s + x2 * c;
    float ss = o1 * o1 + o2 * o2;
    #pragma unroll
    for (int off = 1; off < 64; off <<= 1) ss += __shfl_xor(ss, off);
    float r = rsqrtf(ss * (1.0f / 128.0f) + RMS_EPS);
    if (isq) r *= Q_SCALE;
    p[lane]      = f2bf(o1 * r);
    p[lane + 64] = f2bf(o2 * r);
  }
}

// ---------------- bf16 GEMM: C[M][N] = A[M][K] * Bt[N][K]^T ----------------
// 128x128 tile, BK=64, 4 waves, gl_lds staging (pre-swizzled source).
// Natural block order (XCD swizzle hurt: FETCH 72->86 MB -- R12).
template<int BF16OUT>
__global__ __launch_bounds__(256) void gemm_bt_kernel(const u16* __restrict__ A,
                                                      const u16* __restrict__ Bt,
                                                      void* __restrict__ Cv,
                                                      int M, int N, int K) {
  __shared__ __align__(16) u16 Asm[128 * 64];
  __shared__ __align__(16) u16 Bsm[128 * 64];
  const int tid = threadIdx.x;
  const int lane = tid & 63;
  const int wid = tid >> 6;
  const int m0 = blockIdx.y * 128, n0 = blockIdx.x * 128;
  const int wm = (wid >> 1) * 64, wn = (wid & 1) * 64;
  const int l15 = lane & 15, l4 = lane >> 4;
  const int csrc = (lane & 7) ^ (lane >> 3);      // pre-swizzled source chunk
  f32x4 acc[4][4] = {};

  for (int k0 = 0; k0 < K; k0 += 64) {
    __syncthreads();
    #pragma unroll
    for (int i = 0; i < 4; ++i) {
      int g = wid * 4 + i;
      int row = g * 8 + (lane >> 3);
      gl_lds16(A  + (size_t)(m0 + row) * K + k0 + csrc * 8, (char*)Asm + g * 1024);
      gl_lds16(Bt + (size_t)(n0 + row) * K + k0 + csrc * 8, (char*)Bsm + g * 1024);
    }
    __syncthreads();
    #pragma unroll
    for (int ks = 0; ks < 2; ++ks) {
      bf16x8 af[4], bfr[4];
      #pragma unroll
      for (int mf = 0; mf < 4; ++mf) {
        int r = wm + mf * 16 + l15;
        int bo = r * 128 + (((ks * 4 + l4) ^ (r & 7)) * 16);
        af[mf] = __builtin_bit_cast(bf16x8, *(const u32x4*)((const char*)Asm + bo));
      }
      #pragma unroll
      for (int nf = 0; nf < 4; ++nf) {
        int r = wn + nf * 16 + l15;
        int bo = r * 128 + (((ks * 4 + l4) ^ (r & 7)) * 16);
        bfr[nf] = __builtin_bit_cast(bf16x8, *(const u32x4*)((const char*)Bsm + bo));
      }
      #pragma unroll
      for (int mf = 0; mf < 4; ++mf)
        #pragma unroll
        for (int nf = 0; nf < 4; ++nf)
          acc[mf][nf] = mfma16(af[mf], bfr[nf], acc[mf][nf]);
    }
  }
  #pragma unroll
  for (int mf = 0; mf < 4; ++mf)
    #pragma unroll
    for (int nf = 0; nf < 4; ++nf)
      #pragma unroll
      for (int reg = 0; reg < 4; ++reg) {
        int row = m0 + wm + mf * 16 + l4 * 4 + reg;
        int col = n0 + wn + nf * 16 + l15;
        float v = acc[mf][nf][reg];
        if (BF16OUT) ((u16*)Cv)[(size_t)row * N + col] = f2bf(v);
        else         ((float*)Cv)[(size_t)row * N + col] = v;
      }
}

// ---------------- sliding-window GQA flash attention (R10 structure + T5 setprio) --------
// Block = 64 q-rows of one (b,h); 4 waves x 16 rows; dbuf prefetch staging.
// Softmax: exp2-domain Q-prescale + defer-rescale + MFMA row-sum (P @ ones).
// T5: setprio(1) around the MFMA clusters -- 4 independent blocks/CU give the
// CU scheduler role diversity to arbitrate (m191 attn regime, +4-7%).
__global__ __launch_bounds__(256, 4) void attn_kernel(const u16* __restrict__ qkv,
                                                      const u16* __restrict__ vt,
                                                      u16* __restrict__ yb,
                                                      const int* __restrict__ wsz_p) {
  __shared__ __align__(16) u16 Ksm[2][64 * 128];  // [key][d], 16-chunk swizzle ^(key&15)
  __shared__ __align__(16) u16 Vsm[2][128 * 64];  // [d][key], 8-chunk swizzle ^(d&7)
  __shared__ __align__(16) u16 Psm[4 * 16 * 64];  // per-wave P 16x64, swizzled

  const int W = wsz_p[0];
  const int tid = threadIdx.x, lane = tid & 63, wid = tid >> 6;
  const int l15 = lane & 15, l4 = lane >> 4;
  const int bid = blockIdx.x;
  const int h   = bid & 15;
  const int b   = (bid >> 4) & 1;
  const int qt  = 31 - (bid >> 5);       // longest first (LPT)
  const int kvh = h >> 2;                // rep = 4
  const size_t tokb = (size_t)b * T_DIM;
  const u16* vtb = vt + ((size_t)(b * H_KV + kvh) * HD) * T_DIM;
  const int rbase = qt * 64 + wid * 16;

  auto stage = [&](int kt, int bufsel) {
    const u16* kp = qkv + (tokb + kt * 64) * NQKV + C_DIM + kvh * HD;
    #pragma unroll
    for (int i = 0; i < 4; ++i) {
      int g = wid * 4 + i;
      int row = g * 4 + (lane >> 4);
      int cs = (lane & 15) ^ (row & 15);
      gl_lds16(kp + (size_t)row * NQKV + cs * 8, (char*)Ksm[bufsel] + g * 1024);
    }
    const u16* vp = vtb + kt * 64;
    #pragma unroll
    for (int i = 0; i < 4; ++i) {
      int g = wid * 4 + i;
      int d = g * 8 + (lane >> 3);
      int cs = (lane & 7) ^ (d & 7);
      gl_lds16(vp + (size_t)d * T_DIM + cs * 8, (char*)Vsm[bufsel] + g * 1024);
    }
  };

  bf16x8 qf[4];
  {
    int r = rbase + l15;
    const u16* qp = qkv + (tokb + r) * NQKV + h * HD;
    #pragma unroll
    for (int ks = 0; ks < 4; ++ks)
      qf[ks] = __builtin_bit_cast(bf16x8, *(const u32x4*)(qp + ks * 32 + l4 * 8));
  }

  const u32x4 onesu = {0x3F803F80u, 0x3F803F80u, 0x3F803F80u, 0x3F803F80u};
  const bf16x8 onesf = __builtin_bit_cast(bf16x8, onesu);   // 8 x bf16(1.0)

  f32x4 yacc[8] = {};
  f32x4 ylsum = {0.f, 0.f, 0.f, 0.f};    // softmax denominator, via P @ ones
  float mrow[4];
  #pragma unroll
  for (int rg = 0; rg < 4; ++rg) mrow[rg] = -3.0e38f;

  int smin = qt * 64 - W; if (smin < 0) smin = 0;
  const int t0 = smin >> 6;
  char* pbase = (char*)Psm + wid * 2048;

  stage(t0, 0);
  __syncthreads();
  int cur = 0;

  for (int kt = t0; kt <= qt; ++kt) {
    if (kt < qt) stage(kt + 1, cur ^ 1);

    const int slo = kt * 64;
    bool active = (slo <= rbase + 15) && ((rbase - (slo + 63)) <= W);
    if (active) {
      // S = Q K^T (exp2 domain; Q pre-scaled)
      float Sc[4][4];
      __builtin_amdgcn_s_setprio(1);
      #pragma unroll
      for (int nf = 0; nf < 4; ++nf) {
        f32x4 sa = {0.f, 0.f, 0.f, 0.f};
        int key = nf * 16 + l15;
        #pragma unroll
        for (int ks = 0; ks < 4; ++ks) {
          int bo = key * 256 + (((ks * 4 + l4) ^ (key & 15)) * 16);
          bf16x8 kf = __builtin_bit_cast(bf16x8, *(const u32x4*)((const char*)Ksm[cur] + bo));
          sa = mfma16(qf[ks], kf, sa);
        }
        #pragma unroll
        for (int rg = 0; rg < 4; ++rg) Sc[nf][rg] = sa[rg];
      }
      __builtin_amdgcn_s_setprio(0);
      // mask only when tile not fully valid for this wave
      bool fullvalid = ((slo + 63) <= rbase) && ((rbase + 15 - slo) <= W);
      if (!fullvalid) {
        #pragma unroll
        for (int nf = 0; nf < 4; ++nf) {
          int s = slo + nf * 16 + l15;
          #pragma unroll
          for (int rg = 0; rg < 4; ++rg) {
            int r = rbase + l4 * 4 + rg;
            if (s > r || (r - s) > W) Sc[nf][rg] = -3.0e38f;
          }
        }
      }
      // tile max per row (wave-reduced over the 16 key-lanes)
      float tmax[4];
      #pragma unroll
      for (int rg = 0; rg < 4; ++rg) {
        float tm = fmaxf(fmaxf(Sc[0][rg], Sc[1][rg]), fmaxf(Sc[2][rg], Sc[3][rg]));
        #pragma unroll
        for (int off = 1; off < 16; off <<= 1) tm = fmaxf(tm, __shfl_xor(tm, off));
        tmax[rg] = tm;
      }
      // T13 defer-rescale: skip when no row's max grew by >8 (P bounded by 2^8)
      bool small = tmax[0] <= mrow[0] + 8.f && tmax[1] <= mrow[1] + 8.f &&
                   tmax[2] <= mrow[2] + 8.f && tmax[3] <= mrow[3] + 8.f;
      if (!__all(small)) {
        f32x4 fv;
        #pragma unroll
        for (int rg = 0; rg < 4; ++rg) {
          float mnew = fmaxf(mrow[rg], tmax[rg]);
          fv[rg] = exp2f(fmaxf(mrow[rg], -1.0e30f) - fmaxf(mnew, -1.0e30f));
          mrow[rg] = mnew;
        }
        #pragma unroll
        for (int nf2 = 0; nf2 < 8; ++nf2) yacc[nf2] *= fv;
        ylsum *= fv;
      }
      float mc[4];
      #pragma unroll
      for (int rg = 0; rg < 4; ++rg) mc[rg] = fmaxf(mrow[rg], -1.0e30f);
      // P = exp2(S - m), truncation-cast to bf16 -> wave-private LDS
      #pragma unroll
      for (int nf = 0; nf < 4; ++nf)
        #pragma unroll
        for (int rg = 0; rg < 4; ++rg) {
          float pv = exp2f(Sc[nf][rg] - mc[rg]);
          unsigned int pbits = __builtin_bit_cast(unsigned int, pv);
          int q   = l4 * 4 + rg;
          int key = nf * 16 + l15;
          int bo = q * 128 + (((key >> 3) ^ (q & 7)) * 16) + (key & 7) * 2;
          *(u16*)(pbase + bo) = (u16)(pbits >> 16);
        }

      // PV: y(16x128) += P(16x64) @ V(64x128);  denominator: ylsum += P @ 1
      #pragma unroll
      for (int ks2 = 0; ks2 < 2; ++ks2) {
        int boA = l15 * 128 + (((ks2 * 4 + l4) ^ (l15 & 7)) * 16);
        bf16x8 pa = __builtin_bit_cast(bf16x8, *(const u32x4*)(pbase + boA));
        __builtin_amdgcn_s_setprio(1);
        ylsum = mfma16(pa, onesf, ylsum);
        #pragma unroll
        for (int nf2 = 0; nf2 < 8; ++nf2) {
          int d = nf2 * 16 + l15;
          int boB = d * 128 + (((ks2 * 4 + l4) ^ (d & 7)) * 16);
          bf16x8 vf = __builtin_bit_cast(bf16x8, *(const u32x4*)((const char*)Vsm[cur] + boB));
          yacc[nf2] = mfma16(pa, vf, yacc[nf2]);
        }
        __builtin_amdgcn_s_setprio(0);
      }
    }
    __syncthreads();
    cur ^= 1;
  }

  // normalize + write y (bf16)
  #pragma unroll
  for (int nf2 = 0; nf2 < 8; ++nf2)
    #pragma unroll
    for (int rg = 0; rg < 4; ++rg) {
      int r = rbase + l4 * 4 + rg;
      float v = yacc[nf2][rg] / ylsum[rg];
      yb[(tokb + r) * (size_t)C_DIM + h * HD + nf2 * 16 + l15] = f2bf(v);
    }
}

// ---------------- launch ----------------
extern "C" void kernel_launch(void* const* d_in, const int* in_sizes, int n_in,
                              void* d_out, int out_size, void* d_ws, size_t ws_size,
                              hipStream_t stream) {
  const float* x    = (const float*)d_in[0];
  const float* cosb = (const float*)d_in[1];
  const float* sinb = (const float*)d_in[2];
  const float* wq   = (const float*)d_in[3];
  const float* wk   = (const float*)d_in[4];
  const float* wv   = (const float*)d_in[5];
  const float* wo   = (const float*)d_in[6];
  const int*   wsz  = (const int*)d_in[7];

  char* ws = (char*)d_ws;
  u16* xb    = (u16*)(ws);                       // 16 MB (dead after QKV GEMM)
  u16* qkvb  = (u16*)(ws + (size_t)16777216);    // 24 MB
  u16* wqkvb = (u16*)(ws + (size_t)41943040);    // 12 MB, [3072][2048]
  u16* wob   = (u16*)(ws + (size_t)54525952);    // 8 MB,  [2048][2048]
  u16* ybuf  = (u16*)(ws + (size_t)62914560);    // 16 MB
  u16* vtb   = (u16*)(ws);                       // 4 MB, reuses xb region

  prep_kernel<<<2560 + 8192, 256, 0, stream>>>(x, wq, wk, wv, wo, xb, wqkvb, wob);
  gemm_bt_kernel<1><<<dim3(NQKV / 128, MTOK / 128), 256, 0, stream>>>(xb, wqkvb, qkvb, MTOK, NQKV, C_DIM);
  ropevt_kernel<<<256 + (MTOK * (H_Q + H_KV)) / 4, 256, 0, stream>>>(qkvb, cosb, sinb, vtb);
  attn_kernel<<<B_DIM * H_Q * (T_DIM / 64), 256, 0, stream>>>(qkvb, vtb, ybuf, wsz);
  gemm_bt_kernel<0><<<dim3(C_DIM / 128, MTOK / 128), 256, 0, stream>>>(ybuf, wob, d_out, MTOK, C_DIM, C_DIM);
}

// Round 15
// 185.084 us; speedup vs baseline: 1.0238x; 1.0121x over previous
//
#include <hip/hip_runtime.h>
#include <stdint.h>

typedef __attribute__((ext_vector_type(4))) float f32x4;
typedef __attribute__((ext_vector_type(8))) __bf16 bf16x8;
typedef __attribute__((ext_vector_type(4))) unsigned int u32x4;
typedef unsigned short u16;

#define B_DIM 2
#define T_DIM 2048
#define C_DIM 2048
#define H_Q   16
#define H_KV  4
#define HD    128
#define NQKV  3072            // 2048 q | 512 k | 512 v
#define MTOK  4096            // B*T
#define RMS_EPS 1.1920928955078125e-07f
// 1/sqrt(128) * log2(e), folded into q's rms scale so S comes out in exp2 domain
#define Q_SCALE 0.12751749f

__device__ __forceinline__ u16 f2bf(float f) {
  union { float f; unsigned int u; } v; v.f = f;
  unsigned int r = v.u + 0x7FFFu + ((v.u >> 16) & 1u);   // RNE
  return (u16)(r >> 16);
}
__device__ __forceinline__ float bf2f(u16 h) {
  union { unsigned int u; float f; } v; v.u = ((unsigned int)h) << 16;
  return v.f;
}
__device__ __forceinline__ f32x4 mfma16(bf16x8 a, bf16x8 b, f32x4 c) {
  return __builtin_amdgcn_mfma_f32_16x16x32_bf16(a, b, c, 0, 0, 0);
}
// async global->LDS, 16B per lane; lds base must be wave-uniform (HW: base + lane*16)
__device__ __forceinline__ void gl_lds16(const void* g, void* l) {
  __builtin_amdgcn_global_load_lds(
      (const __attribute__((address_space(1))) unsigned int*)g,
      (__attribute__((address_space(3))) unsigned int*)l, 16, 0, 0);
}

// ---------------- prep: weight transposes (blocks 0..2559) + x cast (rest) ----------------
__global__ __launch_bounds__(256) void prep_kernel(const float* __restrict__ x,
                                                   const float* __restrict__ wq,
                                                   const float* __restrict__ wk,
                                                   const float* __restrict__ wv,
                                                   const float* __restrict__ wo,
                                                   u16* __restrict__ xb,
                                                   u16* __restrict__ wqkvb,
                                                   u16* __restrict__ wob) {
  __shared__ float tile[64][65];
  int bid = blockIdx.x, t = threadIdx.x;
  if (bid < 2560) {                       // transpose+cast fp32 [K][N] -> bf16 [N][2048]
    int nb = bid % 80, kb = bid / 80;
    const float* src; u16* dst; int srcN, nloc;
    if (nb < 32)      { src = wq; srcN = 2048; nloc = nb;      dst = wqkvb; }
    else if (nb < 40) { src = wk; srcN = 512;  nloc = nb - 32; dst = wqkvb + (size_t)2048 * 2048; }
    else if (nb < 48) { src = wv; srcN = 512;  nloc = nb - 40; dst = wqkvb + (size_t)2560 * 2048; }
    else              { src = wo; srcN = 2048; nloc = nb - 48; dst = wob; }
    int n0 = nloc * 64, k0 = kb * 64;
    #pragma unroll
    for (int idx = t; idx < 4096; idx += 256) {
      int r = idx >> 6, c = idx & 63;
      tile[r][c] = src[(size_t)(k0 + r) * srcN + n0 + c];
    }
    __syncthreads();
    #pragma unroll
    for (int idx = t; idx < 4096; idx += 256) {
      int r = idx >> 6, c = idx & 63;
      dst[(size_t)(n0 + r) * 2048 + k0 + c] = f2bf(tile[c][r]);
    }
  } else {                                // cast x
    int i = ((bid - 2560) * 256 + t) * 4;
    if (i >= MTOK * C_DIM) return;
    float4 v = *(const float4*)(x + i);
    u16 o0 = f2bf(v.x), o1 = f2bf(v.y), o2 = f2bf(v.z), o3 = f2bf(v.w);
    unsigned int lo = (unsigned int)o0 | ((unsigned int)o1 << 16);
    unsigned int hi = (unsigned int)o2 | ((unsigned int)o3 << 16);
    *(uint2*)(xb + i) = make_uint2(lo, hi);
  }
}

// ---------------- rope+rms (in place on q,k) + V^T precompute, one dispatch ----------------
// q heads additionally scaled by Q_SCALE so attention scores land in exp2 domain.
__global__ __launch_bounds__(256) void ropevt_kernel(u16* __restrict__ qkv,
                                                     const float* __restrict__ cosb,
                                                     const float* __restrict__ sinb,
                                                     u16* __restrict__ vt) {
  __shared__ __align__(16) u16 tile[64][136];
  int bid = blockIdx.x, tid = threadIdx.x;
  if (bid < 256) {                        // vtrans: qkv v-section -> vt[b][kvh][d][T]
    int tt0 = (bid & 31) * 64;
    int kvh = (bid >> 5) & 3;
    int b   = bid >> 7;
    const u16* vp = qkv + ((size_t)b * T_DIM + tt0) * NQKV + C_DIM + H_KV * HD + kvh * HD;
    #pragma unroll
    for (int i = 0; i < 4; ++i) {
      int cid = tid + i * 256;
      int r = cid >> 4, c = cid & 15;
      u32x4 v = *(const u32x4*)(vp + (size_t)r * NQKV + c * 8);
      *(u32x4*)&tile[r][c * 8] = v;
    }
    __syncthreads();
    u16* op = vt + ((size_t)(b * H_KV + kvh) * HD) * T_DIM + tt0;
    #pragma unroll
    for (int i = 0; i < 4; ++i) {
      int cid = tid + i * 256;
      int d = cid >> 3, tc = cid & 7;
      u16 vals[8];
      #pragma unroll
      for (int j = 0; j < 8; ++j) vals[j] = tile[tc * 8 + j][d];
      u32x4 w;
      w.x = (unsigned int)vals[0] | ((unsigned int)vals[1] << 16);
      w.y = (unsigned int)vals[2] | ((unsigned int)vals[3] << 16);
      w.z = (unsigned int)vals[4] | ((unsigned int)vals[5] << 16);
      w.w = (unsigned int)vals[6] | ((unsigned int)vals[7] << 16);
      *(u32x4*)(op + (size_t)d * T_DIM + tc * 8) = w;
    }
  } else {                                // rope+rms: one wave per (token, head)
    int gw = ((bid - 256) * 256 + tid) >> 6;
    int lane = tid & 63;
    int hh = gw % (H_Q + H_KV);
    int tok = gw / (H_Q + H_KV);
    int t = tok & (T_DIM - 1);
    bool isq = (hh < H_Q);
    int base = isq ? hh * HD : (C_DIM + (hh - H_Q) * HD);
    u16* p = qkv + (size_t)tok * NQKV + base;
    float x1 = bf2f(p[lane]);
    float x2 = bf2f(p[lane + 64]);
    float c = cosb[t * 64 + lane];
    float s = sinb[t * 64 + lane];
    float o1 =  x1 * c + x2 * s;
    float o2 = -x1 * s + x2 * c;
    float ss = o1 * o1 + o2 * o2;
    #pragma unroll
    for (int off = 1; off < 64; off <<= 1) ss += __shfl_xor(ss, off);
    float r = rsqrtf(ss * (1.0f / 128.0f) + RMS_EPS);
    if (isq) r *= Q_SCALE;
    p[lane]      = f2bf(o1 * r);
    p[lane + 64] = f2bf(o2 * r);
  }
}

// ---------------- bf16 GEMM: C[M][N] = A[M][K] * Bt[N][K]^T ----------------
// 128x128 tile, BK=64, 4 waves, gl_lds staging (pre-swizzled source).
// Natural block order (XCD swizzle hurt: FETCH 72->86 MB -- R12).
template<int BF16OUT>
__global__ __launch_bounds__(256) void gemm_bt_kernel(const u16* __restrict__ A,
                                                      const u16* __restrict__ Bt,
                                                      void* __restrict__ Cv,
                                                      int M, int N, int K) {
  __shared__ __align__(16) u16 Asm[128 * 64];
  __shared__ __align__(16) u16 Bsm[128 * 64];
  const int tid = threadIdx.x;
  const int lane = tid & 63;
  const int wid = tid >> 6;
  const int m0 = blockIdx.y * 128, n0 = blockIdx.x * 128;
  const int wm = (wid >> 1) * 64, wn = (wid & 1) * 64;
  const int l15 = lane & 15, l4 = lane >> 4;
  const int csrc = (lane & 7) ^ (lane >> 3);      // pre-swizzled source chunk
  f32x4 acc[4][4] = {};

  for (int k0 = 0; k0 < K; k0 += 64) {
    __syncthreads();
    #pragma unroll
    for (int i = 0; i < 4; ++i) {
      int g = wid * 4 + i;
      int row = g * 8 + (lane >> 3);
      gl_lds16(A  + (size_t)(m0 + row) * K + k0 + csrc * 8, (char*)Asm + g * 1024);
      gl_lds16(Bt + (size_t)(n0 + row) * K + k0 + csrc * 8, (char*)Bsm + g * 1024);
    }
    __syncthreads();
    #pragma unroll
    for (int ks = 0; ks < 2; ++ks) {
      bf16x8 af[4], bfr[4];
      #pragma unroll
      for (int mf = 0; mf < 4; ++mf) {
        int r = wm + mf * 16 + l15;
        int bo = r * 128 + (((ks * 4 + l4) ^ (r & 7)) * 16);
        af[mf] = __builtin_bit_cast(bf16x8, *(const u32x4*)((const char*)Asm + bo));
      }
      #pragma unroll
      for (int nf = 0; nf < 4; ++nf) {
        int r = wn + nf * 16 + l15;
        int bo = r * 128 + (((ks * 4 + l4) ^ (r & 7)) * 16);
        bfr[nf] = __builtin_bit_cast(bf16x8, *(const u32x4*)((const char*)Bsm + bo));
      }
      #pragma unroll
      for (int mf = 0; mf < 4; ++mf)
        #pragma unroll
        for (int nf = 0; nf < 4; ++nf)
          acc[mf][nf] = mfma16(af[mf], bfr[nf], acc[mf][nf]);
    }
  }
  #pragma unroll
  for (int mf = 0; mf < 4; ++mf)
    #pragma unroll
    for (int nf = 0; nf < 4; ++nf)
      #pragma unroll
      for (int reg = 0; reg < 4; ++reg) {
        int row = m0 + wm + mf * 16 + l4 * 4 + reg;
        int col = n0 + wn + nf * 16 + l15;
        float v = acc[mf][nf][reg];
        if (BF16OUT) ((u16*)Cv)[(size_t)row * N + col] = f2bf(v);
        else         ((float*)Cv)[(size_t)row * N + col] = v;
      }
}

// ---------------- sliding-window GQA flash attention (swapped-QK, in-register P) --------
// Block = 64 q-rows of one (b,h); 4 waves x 16 rows; dbuf prefetch staging.
// QK^T computed SWAPPED: mfma(K,Q) -> lane owns one q-row (q = l15), keys in
// (l4,reg): row-max = 15 fmax + 2 shfl; softmax state is one scalar/lane.
// P goes to PV's A-fragments IN-REGISTER (pack + 16 shfl + 8 selects) -- the
// LDS P round-trip and its address math are deleted (Psm gone).
// Denominator via MFMA row-sum (P @ ones); T13 defer-rescale.
__global__ __launch_bounds__(256, 4) void attn_kernel(const u16* __restrict__ qkv,
                                                      const u16* __restrict__ vt,
                                                      u16* __restrict__ yb,
                                                      const int* __restrict__ wsz_p) {
  __shared__ __align__(16) u16 Ksm[2][64 * 128];  // [key][d], 16-chunk swizzle ^(key&15)
  __shared__ __align__(16) u16 Vsm[2][128 * 64];  // [d][key], 8-chunk swizzle ^(d&7)

  const int W = wsz_p[0];
  const int tid = threadIdx.x, lane = tid & 63, wid = tid >> 6;
  const int l15 = lane & 15, l4 = lane >> 4;
  const int bid = blockIdx.x;
  const int h   = bid & 15;
  const int b   = (bid >> 4) & 1;
  const int qt  = 31 - (bid >> 5);       // longest first (LPT)
  const int kvh = h >> 2;                // rep = 4
  const size_t tokb = (size_t)b * T_DIM;
  const u16* vtb = vt + ((size_t)(b * H_KV + kvh) * HD) * T_DIM;
  const int rbase = qt * 64 + wid * 16;

  auto stage = [&](int kt, int bufsel) {
    const u16* kp = qkv + (tokb + kt * 64) * NQKV + C_DIM + kvh * HD;
    #pragma unroll
    for (int i = 0; i < 4; ++i) {
      int g = wid * 4 + i;
      int row = g * 4 + (lane >> 4);
      int cs = (lane & 15) ^ (row & 15);
      gl_lds16(kp + (size_t)row * NQKV + cs * 8, (char*)Ksm[bufsel] + g * 1024);
    }
    const u16* vp = vtb + kt * 64;
    #pragma unroll
    for (int i = 0; i < 4; ++i) {
      int g = wid * 4 + i;
      int d = g * 8 + (lane >> 3);
      int cs = (lane & 7) ^ (d & 7);
      gl_lds16(vp + (size_t)d * T_DIM + cs * 8, (char*)Vsm[bufsel] + g * 1024);
    }
  };

  bf16x8 qf[4];
  {
    int r = rbase + l15;
    const u16* qp = qkv + (tokb + r) * NQKV + h * HD;
    #pragma unroll
    for (int ks = 0; ks < 4; ++ks)
      qf[ks] = __builtin_bit_cast(bf16x8, *(const u32x4*)(qp + ks * 32 + l4 * 8));
  }

  const u32x4 onesu = {0x3F803F80u, 0x3F803F80u, 0x3F803F80u, 0x3F803F80u};
  const bf16x8 onesf = __builtin_bit_cast(bf16x8, onesu);   // 8 x bf16(1.0)

  f32x4 yacc[8] = {};
  f32x4 ylsum = {0.f, 0.f, 0.f, 0.f};    // softmax denominator, via P @ ones
  float mq = -3.0e38f;                   // running max for q-row (lane&15)

  int smin = qt * 64 - W; if (smin < 0) smin = 0;
  const int t0 = smin >> 6;
  // shfl source lanes for in-register P redistribution (same l15 column)
  const int idxA = l15 + ((l4 & 1) << 5);   // source lane-group 2*(l4&1)
  const int idxB = idxA + 16;               // source lane-group 2*(l4&1)+1
  const bool hiNf = ((l4 >> 1) & 1) != 0;

  stage(t0, 0);
  __syncthreads();
  int cur = 0;

  for (int kt = t0; kt <= qt; ++kt) {
    if (kt < qt) stage(kt + 1, cur ^ 1);

    const int slo = kt * 64;
    bool active = (slo <= rbase + 15) && ((rbase - (slo + 63)) <= W);
    if (active) {
      // S^T = K Q^T (swapped): Sc[nf][reg] = S[key = slo+nf*16+l4*4+reg][q = rbase+l15]
      float Sc[4][4];
      __builtin_amdgcn_s_setprio(1);
      #pragma unroll
      for (int nf = 0; nf < 4; ++nf) {
        f32x4 sa = {0.f, 0.f, 0.f, 0.f};
        int key = nf * 16 + l15;           // fragment load unchanged (A/B maps identical)
        #pragma unroll
        for (int ks = 0; ks < 4; ++ks) {
          int bo = key * 256 + (((ks * 4 + l4) ^ (key & 15)) * 16);
          bf16x8 kf = __builtin_bit_cast(bf16x8, *(const u32x4*)((const char*)Ksm[cur] + bo));
          sa = mfma16(kf, qf[ks], sa);     // SWAPPED: K as A, Q as B
        }
        #pragma unroll
        for (int rg = 0; rg < 4; ++rg) Sc[nf][rg] = sa[rg];
      }
      __builtin_amdgcn_s_setprio(0);
      // mask: key = slo + nf*16 + l4*4 + reg ; q = rbase + l15
      bool fullvalid = ((slo + 63) <= rbase) && ((rbase + 15 - slo) <= W);
      if (!fullvalid) {
        int q = rbase + l15;
        #pragma unroll
        for (int nf = 0; nf < 4; ++nf)
          #pragma unroll
          for (int rg = 0; rg < 4; ++rg) {
            int s = slo + nf * 16 + l4 * 4 + rg;
            if (s > q || (q - s) > W) Sc[nf][rg] = -3.0e38f;
          }
      }
      // per-q tile max: 15 local fmax + 2 shfl (over the 4-lane l4 group)
      float tm = Sc[0][0];
      #pragma unroll
      for (int nf = 0; nf < 4; ++nf)
        #pragma unroll
        for (int rg = 0; rg < 4; ++rg) tm = fmaxf(tm, Sc[nf][rg]);
      tm = fmaxf(tm, __shfl_xor(tm, 16));
      tm = fmaxf(tm, __shfl_xor(tm, 32));
      // T13 defer-rescale
      if (!__all(tm <= mq + 8.f)) {
        float mnew = fmaxf(mq, tm);
        float fq = exp2f(fmaxf(mq, -1.0e30f) - fmaxf(mnew, -1.0e30f));
        mq = mnew;
        f32x4 fv;
        #pragma unroll
        for (int rg = 0; rg < 4; ++rg) {
          int ql = l4 * 4 + rg;            // yacc row q-local
          fv[rg] = __shfl(fq, (lane & 0x30) | ql);
        }
        #pragma unroll
        for (int nf2 = 0; nf2 < 8; ++nf2) yacc[nf2] *= fv;
        ylsum *= fv;
      }
      // P = exp2(S - m), truncation-packed to bf16 pairs (reg 0,1 | 2,3)
      float mqc = fmaxf(mq, -1.0e30f);
      unsigned int P32[4][2];
      #pragma unroll
      for (int nf = 0; nf < 4; ++nf) {
        unsigned int b0 = __builtin_bit_cast(unsigned int, exp2f(Sc[nf][0] - mqc));
        unsigned int b1 = __builtin_bit_cast(unsigned int, exp2f(Sc[nf][1] - mqc));
        unsigned int b2 = __builtin_bit_cast(unsigned int, exp2f(Sc[nf][2] - mqc));
        unsigned int b3 = __builtin_bit_cast(unsigned int, exp2f(Sc[nf][3] - mqc));
        P32[nf][0] = (b1 & 0xFFFF0000u) | (b0 >> 16);
        P32[nf][1] = (b3 & 0xFFFF0000u) | (b2 >> 16);
      }

      // PV: assemble pa in-register; y(16x128) += P(16x64) @ V(64x128)
      #pragma unroll
      for (int ks2 = 0; ks2 < 2; ++ks2) {
        int nf0 = 2 * ks2, nf1 = 2 * ks2 + 1;
        unsigned int a00 = __shfl(P32[nf0][0], idxA), a10 = __shfl(P32[nf1][0], idxA);
        unsigned int a01 = __shfl(P32[nf0][1], idxA), a11 = __shfl(P32[nf1][1], idxA);
        unsigned int b00 = __shfl(P32[nf0][0], idxB), b10 = __shfl(P32[nf1][0], idxB);
        unsigned int b01 = __shfl(P32[nf0][1], idxB), b11 = __shfl(P32[nf1][1], idxB);
        u32x4 paw;
        paw.x = hiNf ? a10 : a00;
        paw.y = hiNf ? a11 : a01;
        paw.z = hiNf ? b10 : b00;
        paw.w = hiNf ? b11 : b01;
        bf16x8 pa = __builtin_bit_cast(bf16x8, paw);
        __builtin_amdgcn_s_setprio(1);
        ylsum = mfma16(pa, onesf, ylsum);
        #pragma unroll
        for (int nf2 = 0; nf2 < 8; ++nf2) {
          int d = nf2 * 16 + l15;
          int boB = d * 128 + (((ks2 * 4 + l4) ^ (d & 7)) * 16);
          bf16x8 vf = __builtin_bit_cast(bf16x8, *(const u32x4*)((const char*)Vsm[cur] + boB));
          yacc[nf2] = mfma16(pa, vf, yacc[nf2]);
        }
        __builtin_amdgcn_s_setprio(0);
      }
    }
    __syncthreads();
    cur ^= 1;
  }

  // normalize + write y (bf16); yacc row = rbase + l4*4 + reg, col = nf2*16 + l15
  #pragma unroll
  for (int nf2 = 0; nf2 < 8; ++nf2)
    #pragma unroll
    for (int rg = 0; rg < 4; ++rg) {
      int r = rbase + l4 * 4 + rg;
      float v = yacc[nf2][rg] / ylsum[rg];
      yb[(tokb + r) * (size_t)C_DIM + h * HD + nf2 * 16 + l15] = f2bf(v);
    }
}

// ---------------- launch ----------------
extern "C" void kernel_launch(void* const* d_in, const int* in_sizes, int n_in,
                              void* d_out, int out_size, void* d_ws, size_t ws_size,
                              hipStream_t stream) {
  const float* x    = (const float*)d_in[0];
  const float* cosb = (const float*)d_in[1];
  const float* sinb = (const float*)d_in[2];
  const float* wq   = (const float*)d_in[3];
  const float* wk   = (const float*)d_in[4];
  const float* wv   = (const float*)d_in[5];
  const float* wo   = (const float*)d_in[6];
  const int*   wsz  = (const int*)d_in[7];

  char* ws = (char*)d_ws;
  u16* xb    = (u16*)(ws);                       // 16 MB (dead after QKV GEMM)
  u16* qkvb  = (u16*)(ws + (size_t)16777216);    // 24 MB
  u16* wqkvb = (u16*)(ws + (size_t)41943040);    // 12 MB, [3072][2048]
  u16* wob   = (u16*)(ws + (size_t)54525952);    // 8 MB,  [2048][2048]
  u16* ybuf  = (u16*)(ws + (size_t)62914560);    // 16 MB
  u16* vtb   = (u16*)(ws);                       // 4 MB, reuses xb region

  prep_kernel<<<2560 + 8192, 256, 0, stream>>>(x, wq, wk, wv, wo, xb, wqkvb, wob);
  gemm_bt_kernel<1><<<dim3(NQKV / 128, MTOK / 128), 256, 0, stream>>>(xb, wqkvb, qkvb, MTOK, NQKV, C_DIM);
  ropevt_kernel<<<256 + (MTOK * (H_Q + H_KV)) / 4, 256, 0, stream>>>(qkvb, cosb, sinb, vtb);
  attn_kernel<<<B_DIM * H_Q * (T_DIM / 64), 256, 0, stream>>>(qkvb, vtb, ybuf, wsz);
  gemm_bt_kernel<0><<<dim3(C_DIM / 128, MTOK / 128), 256, 0, stream>>>(ybuf, wob, d_out, MTOK, C_DIM, C_DIM);
}